// Round 13
// baseline (92.876 us; speedup 1.0000x reference)
//
#include <hip/hip_runtime.h>
#include <math.h>

// Fused: out[b,oc,y,x] = max_{dy,dx} min(xmax[b,y+dy-2,x+dx-2], k[oc,dy,dx])
// xmax = channel-max over C=32; OOB = -inf.
// x (16,32,256,256) f32, k (32,5,5) f32, out (16,32,256,256) f32.
//
// PRODUCER/CONSUMER WAVE SPECIALIZATION (round-8 phases overlap by
// construction; register footprints separated by wave role -> no spill):
//   block = 640 threads: waves 0-1 produce (chanmax -> LDS double buffer),
//   waves 2-9 consume (conv, 4 oc/wave, nt-stores).
//   Block owns a strip of NT=4 stacked 32x16 tiles; producer fills tile t+1
//   while consumers process tile t. lgkm-only barriers (stores not drained).
// 512 blocks = 2/CU; __launch_bounds__(640,5) caps VGPR at 102 -> resident.

#define BATCH 16
#define CH    32
#define OCH   32
#define HH    256
#define WW    256
#define HWSZ  (HH * WW)
#define LH    20              // 16 + 4 halo rows
#define LW    42              // 40 data cols + 2 pad (8B-aligned float2 rows)
#define KP    28              // padded tap row (16B-aligned)
#define NT    4               // tiles per block strip (64 rows)
#define NWG   512             // 16 batch x 8 xstrip x 4 ystrip

typedef float floatx4 __attribute__((ext_vector_type(4)));

__device__ __forceinline__ float vmax3(float a, float b, float c) {
    float d;
    asm("v_max3_f32 %0, %1, %2, %3" : "=v"(d) : "v"(a), "v"(b), "v"(c));
    return d;
}

// Drain LDS ops only; leave nt-stores in flight across the block sync.
__device__ __forceinline__ void lgkm_barrier() {
    asm volatile("s_waitcnt lgkmcnt(0)" ::: "memory");
    __builtin_amdgcn_s_barrier();
}

__global__ __launch_bounds__(640, 5) void fused_maxmin_kernel(const float* __restrict__ x,
                                                              const float* __restrict__ kk,
                                                              float* __restrict__ out) {
    __shared__ float xmt[2][LH][LW];   // double-buffered chanmax halo tiles
    __shared__ float lk[OCH * KP];     // taps, 16B-aligned rows

    int tid = threadIdx.x;
    int bid = blockIdx.x;
    int swz = (bid & 7) * (NWG >> 3) + (bid >> 3);   // XCD-chunked, bijective
    int b   = swz >> 5;                              // batch
    int s   = swz & 31;
    int ys  = s >> 3;                                // 0..3 (64-row strip)
    int xs  = s & 7;                                 // 0..7 (32-col strip)
    int row0 = ys * 64;

    const float NI = -INFINITY;

    for (int i = tid; i < OCH * 25; i += 640)
        lk[(i / 25) * KP + (i % 25)] = kk[i];

    const float4* xb4 = (const float4*)x + (size_t)b * CH * (HWSZ / 4);
    int wave = tid >> 6;

    if (wave < 2) {
        // ---------------- PRODUCER (128 threads) ----------------
        // 200 granules (20 rows x 10 float4 cols): g1 = tid, g2 = tid+128 (<200).
        int pr1 = tid / 10,        pc1 = tid % 10;
        int g2  = tid + 128;
        bool has2 = tid < 72;
        int pr2 = g2 / 10,         pc2 = g2 % 10;
        int c41 = xs * 8 - 1 + pc1;
        int c42 = xs * 8 - 1 + pc2;
        bool cv1 = (c41 >= 0) && (c41 < WW / 4);
        bool cv2 = (c42 >= 0) && (c42 < WW / 4);
        int c41c = c41 < 0 ? 0 : (c41 > WW / 4 - 1 ? WW / 4 - 1 : c41);
        int c42c = c42 < 0 ? 0 : (c42 > WW / 4 - 1 ? WW / 4 - 1 : c42);

        auto produce = [&](int t, int bf) {
            int ybase = row0 + 16 * t - 2;
            {
                int rw = ybase + pr1;
                bool ok = cv1 && (rw >= 0) && (rw < HH);
                int rwc = rw < 0 ? 0 : (rw > HH - 1 ? HH - 1 : rw);
                const float4* src = xb4 + (size_t)rwc * (WW / 4) + c41c;
                float4 m = src[0];
#pragma unroll
                for (int c = 1; c < CH; ++c) {
                    float4 v = src[(size_t)c * (HWSZ / 4)];
                    m.x = fmaxf(m.x, v.x); m.y = fmaxf(m.y, v.y);
                    m.z = fmaxf(m.z, v.z); m.w = fmaxf(m.w, v.w);
                }
                if (!ok) { m.x = NI; m.y = NI; m.z = NI; m.w = NI; }
                *(float2*)&xmt[bf][pr1][4 * pc1]     = make_float2(m.x, m.y);
                *(float2*)&xmt[bf][pr1][4 * pc1 + 2] = make_float2(m.z, m.w);
            }
            if (has2) {
                int rw = ybase + pr2;
                bool ok = cv2 && (rw >= 0) && (rw < HH);
                int rwc = rw < 0 ? 0 : (rw > HH - 1 ? HH - 1 : rw);
                const float4* src = xb4 + (size_t)rwc * (WW / 4) + c42c;
                float4 m = src[0];
#pragma unroll
                for (int c = 1; c < CH; ++c) {
                    float4 v = src[(size_t)c * (HWSZ / 4)];
                    m.x = fmaxf(m.x, v.x); m.y = fmaxf(m.y, v.y);
                    m.z = fmaxf(m.z, v.z); m.w = fmaxf(m.w, v.w);
                }
                if (!ok) { m.x = NI; m.y = NI; m.z = NI; m.w = NI; }
                *(float2*)&xmt[bf][pr2][4 * pc2]     = make_float2(m.x, m.y);
                *(float2*)&xmt[bf][pr2][4 * pc2 + 2] = make_float2(m.z, m.w);
            }
        };

        produce(0, 0);
        lgkm_barrier();
        for (int t = 0; t < NT; ++t) {
            if (t + 1 < NT) produce(t + 1, (t + 1) & 1);
            lgkm_barrier();
        }
    } else {
        // ---------------- CONSUMER (512 threads) ----------------
        int ctid = tid - 128;
        int lane = ctid & 63;
        int cw   = __builtin_amdgcn_readfirstlane(ctid >> 6);   // 0..7
        int xg   = lane & 7;                                    // 4 px
        int rg   = lane >> 3;                                   // 2 rows
        int ocb  = cw * 4;

        lgkm_barrier();                    // wait for tile-0 fill
        for (int t = 0; t < NT; ++t) {
            int bf = t & 1;
            float w[6][8];
#pragma unroll
            for (int r = 0; r < 6; ++r) {
                const float* rp = &xmt[bf][2 * rg + r][4 * xg + 2];
#pragma unroll
                for (int s2 = 0; s2 < 4; ++s2)
                    *(float2*)&w[r][2 * s2] = *(const float2*)(rp + 2 * s2);
            }
            size_t ob = (size_t)(b * OCH + ocb) * HWSZ
                      + (size_t)(row0 + 16 * t + 2 * rg) * WW + xs * 32 + 4 * xg;
#pragma unroll
            for (int o = 0; o < 4; ++o) {
                const float* kv = &lk[(ocb + o) * KP];
                float4 q0 = *(const float4*)(kv + 0);
                float4 q1 = *(const float4*)(kv + 4);
                float4 q2 = *(const float4*)(kv + 8);
                float4 q3 = *(const float4*)(kv + 12);
                float4 q4 = *(const float4*)(kv + 16);
                float4 q5 = *(const float4*)(kv + 20);
                float  k24 = kv[24];
                float kr[25] = { q0.x,q0.y,q0.z,q0.w, q1.x,q1.y,q1.z,q1.w,
                                 q2.x,q2.y,q2.z,q2.w, q3.x,q3.y,q3.z,q3.w,
                                 q4.x,q4.y,q4.z,q4.w, q5.x,q5.y,q5.z,q5.w, k24 };
                float* op = out + ob + (size_t)o * HWSZ;
#pragma unroll
                for (int r = 0; r < 2; ++r) {
                    float a[4];
#pragma unroll
                    for (int j = 0; j < 4; ++j) {
                        float m[25];
#pragma unroll
                        for (int dy = 0; dy < 5; ++dy)
#pragma unroll
                            for (int dx = 0; dx < 5; ++dx)
                                m[dy * 5 + dx] = fminf(w[r + dy][j + dx], kr[dy * 5 + dx]);
                        float t0 = vmax3(m[0],  m[1],  m[2]);
                        float t1 = vmax3(m[3],  m[4],  m[5]);
                        float t2 = vmax3(m[6],  m[7],  m[8]);
                        float t3 = vmax3(m[9],  m[10], m[11]);
                        float t4 = vmax3(m[12], m[13], m[14]);
                        float t5 = vmax3(m[15], m[16], m[17]);
                        float t6 = vmax3(m[18], m[19], m[20]);
                        float t7 = vmax3(m[21], m[22], m[23]);
                        a[j] = vmax3(vmax3(t0, t1, t2), vmax3(t3, t4, t5),
                                     vmax3(t6, t7, m[24]));
                    }
                    floatx4 ov = { a[0], a[1], a[2], a[3] };
                    __builtin_nontemporal_store(ov, (floatx4*)(op + (size_t)r * WW));
                }
            }
            lgkm_barrier();
        }
    }
}

extern "C" void kernel_launch(void* const* d_in, const int* in_sizes, int n_in,
                              void* d_out, int out_size, void* d_ws, size_t ws_size,
                              hipStream_t stream) {
    const float* x  = (const float*)d_in[0];
    const float* kk = (const float*)d_in[1];
    float* out      = (float*)d_out;
    fused_maxmin_kernel<<<NWG, 640, 0, stream>>>(x, kk, out);
}

// Round 14
// 86.138 us; speedup vs baseline: 1.0782x; 1.0782x over previous
//
#include <hip/hip_runtime.h>
#include <math.h>

// Fused: out[b,oc,y,x] = max_{dy,dx} min(xmax[b,y+dy-2,x+dx-2], k[oc,dy,dx])
// xmax = channel-max over C=32; OOB = -inf.
// x (16,32,256,256) f32, k (32,5,5) f32, out (16,32,256,256) f32.
//
// BARRIER-FREE WAVE-AUTONOMOUS TILES (convoy-breaking):
//   wave = one 32x8 output tile, ALL 32 oc, private LDS slice.
//   phase1: 12x40 halo chanmax -> own LDS (2 granules/lane);
//   s_waitcnt lgkmcnt(0) only (wave-coherent -- NO s_barrier anywhere);
//   phase2: round-9 lane map (4px x 1row), window 5x8 = 40 VGPR, 32-oc loop.
// No block sync => 16 waves/CU free-run and self-stagger: read stalls of one
// wave hide under conv of others. No extra per-thread pipeline state => no
// spill (the failure mode of rounds 10/11/13).

#define BATCH 16
#define CH    32
#define OCH   32
#define HH    256
#define WW    256
#define HWSZ  (HH * WW)
#define LH    12              // 8 + 4 halo rows
#define LW    44              // 40 data cols + 4 pad; granules 16B-aligned
#define NWG   1024            // 4096 wave-tiles / 4 waves per block

typedef float floatx4 __attribute__((ext_vector_type(4)));

__device__ __forceinline__ float vmax3(float a, float b, float c) {
    float d;
    asm("v_max3_f32 %0, %1, %2, %3" : "=v"(d) : "v"(a), "v"(b), "v"(c));
    return d;
}

__global__ __launch_bounds__(256, 4) void fused_maxmin_kernel(const float* __restrict__ x,
                                                              const float* __restrict__ kk,
                                                              float* __restrict__ out) {
    __shared__ float xs[4][LH][LW];            // per-wave private slices (8448 B)
    int tid  = threadIdx.x;
    int wv   = tid >> 6;
    int lane = tid & 63;
    int bid  = blockIdx.x;
    int swz  = (bid & 7) * (NWG >> 3) + (bid >> 3);  // XCD-chunked, bijective
    int tile = swz * 4 + wv;                         // 0..4095
    int b    = tile >> 8;                            // 256 tiles/batch
    int t2   = tile & 255;
    int ty   = t2 >> 3;                              // 0..31 (8-row bands)
    int tx   = t2 & 7;                               // 0..7  (32-col bands)
    int row0 = ty * 8;

    const float NI = -INFINITY;
    const float4* xb4 = (const float4*)x + (size_t)b * CH * (HWSZ / 4);
    float* Ls = &xs[wv][0][0];

    // ---- phase1: 120 granules (12 rows x 10 float4), 2 per lane ----
#pragma unroll
    for (int gi = 0; gi < 2; ++gi) {
        int g = lane + 64 * gi;
        if (g < 120) {
            int pr = g / 10, pc = g % 10;
            int c4 = tx * 8 - 1 + pc;
            int rw = row0 - 2 + pr;
            bool valid = (c4 >= 0) && (c4 < WW / 4) && (rw >= 0) && (rw < HH);
            int c4c = c4 < 0 ? 0 : (c4 > WW / 4 - 1 ? WW / 4 - 1 : c4);
            int rwc = rw < 0 ? 0 : (rw > HH - 1 ? HH - 1 : rw);
            const float4* src = xb4 + (size_t)rwc * (WW / 4) + c4c;
            float4 m = src[0];
#pragma unroll
            for (int c = 1; c < CH; ++c) {
                float4 v = src[(size_t)c * (HWSZ / 4)];
                m.x = fmaxf(m.x, v.x); m.y = fmaxf(m.y, v.y);
                m.z = fmaxf(m.z, v.z); m.w = fmaxf(m.w, v.w);
            }
            if (!valid) { m.x = NI; m.y = NI; m.z = NI; m.w = NI; }
            *(float4*)(Ls + pr * LW + 4 * pc) = m;   // 16B-aligned (44%4==0)
        }
    }
    // Wave-coherent LDS visibility; NO s_barrier (waves stay independent).
    asm volatile("s_waitcnt lgkmcnt(0)" ::: "memory");

    // ---- phase2: lane = 4px x 1row; window rows rw..rw+4, cols 4xg+2..+9 ----
    int xg = lane & 7;
    int rw = lane >> 3;
    float w[5][8];
#pragma unroll
    for (int r = 0; r < 5; ++r) {
        const float* rp = Ls + (rw + r) * LW + 4 * xg + 2;
#pragma unroll
        for (int s = 0; s < 4; ++s)
            *(float2*)&w[r][2 * s] = *(const float2*)(rp + 2 * s);
    }

    size_t obase = (size_t)b * OCH * HWSZ + (size_t)(row0 + rw) * WW + tx * 32 + 4 * xg;

#pragma unroll 2
    for (int o = 0; o < OCH; ++o) {
        const float* kv = kk + o * 25;               // L1-resident after first wave
        float4 q0 = *(const float4*)(kv + 0);
        float4 q1 = *(const float4*)(kv + 4);
        float4 q2 = *(const float4*)(kv + 8);
        float4 q3 = *(const float4*)(kv + 12);
        float4 q4 = *(const float4*)(kv + 16);
        float4 q5 = *(const float4*)(kv + 20);
        float  k24 = kv[24];
        float kr[25] = { q0.x,q0.y,q0.z,q0.w, q1.x,q1.y,q1.z,q1.w,
                         q2.x,q2.y,q2.z,q2.w, q3.x,q3.y,q3.z,q3.w,
                         q4.x,q4.y,q4.z,q4.w, q5.x,q5.y,q5.z,q5.w, k24 };

        float a[4];
#pragma unroll
        for (int j = 0; j < 4; ++j) {
            float m[25];
#pragma unroll
            for (int dy = 0; dy < 5; ++dy)
#pragma unroll
                for (int dx = 0; dx < 5; ++dx)
                    m[dy * 5 + dx] = fminf(w[dy][j + dx], kr[dy * 5 + dx]);
            float t0 = vmax3(m[0],  m[1],  m[2]);
            float t1 = vmax3(m[3],  m[4],  m[5]);
            float t2 = vmax3(m[6],  m[7],  m[8]);
            float t3 = vmax3(m[9],  m[10], m[11]);
            float t4 = vmax3(m[12], m[13], m[14]);
            float t5 = vmax3(m[15], m[16], m[17]);
            float t6 = vmax3(m[18], m[19], m[20]);
            float t7 = vmax3(m[21], m[22], m[23]);
            a[j] = vmax3(vmax3(t0, t1, t2), vmax3(t3, t4, t5), vmax3(t6, t7, m[24]));
        }
        floatx4 ov = { a[0], a[1], a[2], a[3] };
        __builtin_nontemporal_store(ov, (floatx4*)(out + obase + (size_t)o * HWSZ));
    }
}

extern "C" void kernel_launch(void* const* d_in, const int* in_sizes, int n_in,
                              void* d_out, int out_size, void* d_ws, size_t ws_size,
                              hipStream_t stream) {
    const float* x  = (const float*)d_in[0];
    const float* kk = (const float*)d_in[1];
    float* out      = (float*)d_out;
    fused_maxmin_kernel<<<NWG, 256, 0, stream>>>(x, kk, out);
}

// Round 15
// 54.618 us; speedup vs baseline: 1.7005x; 1.5771x over previous
//
#include <hip/hip_runtime.h>
#include <math.h>

// Fused maxmin-conv with SORTED-TAP EARLY EXIT.
// out[b,oc,y,x] = max_{t} min(p_t, k_t) over 25 taps. Process taps in
// descending k order; stop when a >= k_next (remaining cands <= k_next <= a).
// EXACT (same max of same mins). With p = chanmax of 32 gaussians (~2.5) and
// |k| <= ~0.5, interior pixels exit after 1 step.
//
// Kernel 1: rank 32x25 taps (rank = #greater, tie by index) -> d_ws entries
//           {k, byte_off_in_LDS_tile} descending + -inf sentinel.
// Kernel 2: round-12 structure (55.3us best): 32x16 tile chanmax -> LDS,
//           phase2 = sorted scan reading taps straight from LDS tile.

#define BATCH 16
#define CH    32
#define OCH   32
#define HH    256
#define WW    256
#define HWSZ  (HH * WW)
#define TW    32
#define TH    16
#define LH    20              // TH + 4
#define LW    42              // LDS tile stride (floats)
#define NWG   (BATCH * (HH / TH) * (WW / TW))   // 2048

typedef float floatx4 __attribute__((ext_vector_type(4)));

// ---- Kernel 1: sort taps by rank (one block, 800 threads) ----
__global__ void sort_taps_kernel(const float* __restrict__ kk, float2* __restrict__ ent) {
    int t = threadIdx.x;
    if (t >= OCH * 25) return;
    int oc = t / 25, i = t % 25;
    float ki = kk[oc * 25 + i];
    int rank = 0;
#pragma unroll
    for (int j = 0; j < 25; ++j) {
        float kj = kk[oc * 25 + j];
        rank += (kj > ki) || (kj == ki && j < i);
    }
    int dy = i / 5, dx = i % 5;
    int off = 4 * (dy * LW + dx);                 // byte offset within LDS tile walk
    ent[oc * 26 + rank] = make_float2(ki, __int_as_float(off));
    if (i == 0) ent[oc * 26 + 25] = make_float2(-INFINITY, __int_as_float(0));
}

__global__ __launch_bounds__(256, 2) void fused_maxmin_kernel(const float* __restrict__ x,
                                                              const float2* __restrict__ gent,
                                                              float* __restrict__ out) {
    __shared__ float xmt[LH][LW];
    __shared__ float2 ent[OCH * 26];
    int tid = threadIdx.x;
    int bid = blockIdx.x;
    int swz = (bid & 7) * (NWG >> 3) + (bid >> 3);   // XCD-chunked, bijective
    int b   = swz >> 7;
    int t2  = swz & 127;
    int ty  = t2 >> 3;
    int tx  = t2 & 7;

    const float NI = -INFINITY;

    // stage sorted tap entries (832 float2, coalesced)
    for (int i = tid; i < OCH * 26; i += 256) ent[i] = gent[i];

    // ---- Phase 1: channel max of 20 rows x 10 float4 granules ----
    if (tid < 200) {
        int pr = tid / 10;
        int pc = tid % 10;
        int c4 = tx * 8 - 1 + pc;
        int rw = ty * TH - 2 + pr;
        bool valid = (c4 >= 0) && (c4 < WW / 4) && (rw >= 0) && (rw < HH);
        int c4c = c4 < 0 ? 0 : (c4 > WW / 4 - 1 ? WW / 4 - 1 : c4);
        int rwc = rw < 0 ? 0 : (rw > HH - 1 ? HH - 1 : rw);
        const float4* src = (const float4*)x + (size_t)b * CH * (HWSZ / 4)
                          + (size_t)rwc * (WW / 4) + c4c;
        float4 m = src[0];
#pragma unroll
        for (int c = 1; c < CH; ++c) {
            float4 v = src[(size_t)c * (HWSZ / 4)];
            m.x = fmaxf(m.x, v.x);
            m.y = fmaxf(m.y, v.y);
            m.z = fmaxf(m.z, v.z);
            m.w = fmaxf(m.w, v.w);
        }
        if (!valid) { m.x = NI; m.y = NI; m.z = NI; m.w = NI; }
        *(float2*)&xmt[pr][4 * pc]     = make_float2(m.x, m.y);
        *(float2*)&xmt[pr][4 * pc + 2] = make_float2(m.z, m.w);
    }
    __syncthreads();

    // ---- Phase 2: sorted-tap scan ----
    int xg = tid & 7;                                // 4 px
    int rg = (tid >> 3) & 7;                         // 2 rows
    int wv = __builtin_amdgcn_readfirstlane(tid >> 6);   // wave -> oc 8wv..8wv+7

    // Tap walk bases: output (r,j) reads (const char*)rp[r] + off + 4j.
    const char* r0p = (const char*)&xmt[2 * rg][4 * xg + 2];
    const char* r1p = (const char*)&xmt[2 * rg + 1][4 * xg + 2];

    size_t obase = (size_t)(b * OCH + wv * 8) * HWSZ
                 + (size_t)(ty * TH + 2 * rg) * WW + tx * TW + 4 * xg;

    for (int o = 0; o < 8; ++o) {
        const float2* E = &ent[(wv * 8 + o) * 26];
        float a00 = NI, a01 = NI, a02 = NI, a03 = NI;
        float a10 = NI, a11 = NI, a12 = NI, a13 = NI;

        for (int i = 0; i < 25; ++i) {
            float2 e  = E[i];                        // uniform -> LDS broadcast
            float  kn = E[i + 1].x;
            float  kv = e.x;
            int    off = __float_as_int(e.y);
            const float* p0 = (const float*)(r0p + off);
            const float* p1 = (const float*)(r1p + off);
            a00 = fmaxf(a00, fminf(p0[0], kv));
            a01 = fmaxf(a01, fminf(p0[1], kv));
            a02 = fmaxf(a02, fminf(p0[2], kv));
            a03 = fmaxf(a03, fminf(p0[3], kv));
            a10 = fmaxf(a10, fminf(p1[0], kv));
            a11 = fmaxf(a11, fminf(p1[1], kv));
            a12 = fmaxf(a12, fminf(p1[2], kv));
            a13 = fmaxf(a13, fminf(p1[3], kv));
            float mn = fminf(fminf(fminf(a00, a01), fminf(a02, a03)),
                             fminf(fminf(a10, a11), fminf(a12, a13)));
            if (__all(mn >= kn)) break;              // remaining cands <= kn <= a
        }

        float* op = out + obase + (size_t)o * HWSZ;
        floatx4 o0 = { a00, a01, a02, a03 };
        floatx4 o1 = { a10, a11, a12, a13 };
        __builtin_nontemporal_store(o0, (floatx4*)op);
        __builtin_nontemporal_store(o1, (floatx4*)(op + WW));
    }
}

extern "C" void kernel_launch(void* const* d_in, const int* in_sizes, int n_in,
                              void* d_out, int out_size, void* d_ws, size_t ws_size,
                              hipStream_t stream) {
    const float* x  = (const float*)d_in[0];
    const float* kk = (const float*)d_in[1];
    float* out      = (float*)d_out;
    float2* ent     = (float2*)d_ws;   // 32*26*8 = 6656 B

    sort_taps_kernel<<<1, OCH * 25, 0, stream>>>(kk, ent);
    fused_maxmin_kernel<<<NWG, 256, 0, stream>>>(x, ent, out);
}